// Round 1
// baseline (121.786 us; speedup 1.0000x reference)
//
#include <hip/hip_runtime.h>
#include <hip/hip_bf16.h>

#define N_NODES 100000
#define N_EDGES 800000
#define D 64

// ---------------------------------------------------------------------------
// The reference's softmax(axis=1) over an [E,1] tensor is identically 1.0,
// so z[n] = count[n] * (node_features[n] @ W_n^T + b_n), where count[n] is
// the number of edges with node0_idx == n. Everything else is dead code.
// ---------------------------------------------------------------------------

// Detect whether the edge-index buffer is int64 (little-endian) or int32.
// For int64 values in [0, N_NODES) every odd int32 word is 0. For genuine
// int32 random indices, P(256 sampled odd words all zero) ~ (1e-5)^256 = 0.
// flag == 0  -> int64 ; flag != 0 -> int32
__global__ void detect_i64_kernel(const int* __restrict__ idx32,
                                  int* __restrict__ flag) {
    int t = threadIdx.x;  // 256 threads, samples first 512 int32 words
    if (idx32[2 * t + 1] != 0) atomicOr(flag, 1);
}

__global__ void hist_kernel(const void* __restrict__ idx_raw,
                            const int* __restrict__ flag,
                            int* __restrict__ cnt) {
    int e = blockIdx.x * blockDim.x + threadIdx.x;
    if (e >= N_EDGES) return;
    int idx;
    if (*flag == 0) {
        idx = (int)((const long long*)idx_raw)[e];   // int64 path
    } else {
        idx = ((const int*)idx_raw)[e];              // int32 path
    }
    atomicAdd(&cnt[idx], 1);
}

// One node per thread. W_n/b_n are addressed with uniform indices only ->
// scalar loads; inner loop is v_fmac_f32 (vgpr, sgpr, vgpr).
__global__ __launch_bounds__(256) void proj_kernel(
        const float* __restrict__ nf,
        const float* __restrict__ Wn,   // [D_OUT=64, D_NODE=64] row-major
        const float* __restrict__ bn,   // [64]
        const int*   __restrict__ cnt,  // [N_NODES]
        float* __restrict__ out) {      // [N_NODES, 64]
    int node = blockIdx.x * 256 + threadIdx.x;
    if (node >= N_NODES) return;

    float acc[D];
#pragma unroll
    for (int o = 0; o < D; ++o) acc[o] = bn[o];

    // K-chunked so only 16 x-values live at a time (acc[64] + x[16] ~ 100 VGPR)
    for (int jc = 0; jc < 4; ++jc) {
        float x[16];
#pragma unroll
        for (int j = 0; j < 4; ++j) {
            const float4 v = *reinterpret_cast<const float4*>(
                &nf[node * D + jc * 16 + j * 4]);
            x[4 * j + 0] = v.x;
            x[4 * j + 1] = v.y;
            x[4 * j + 2] = v.z;
            x[4 * j + 3] = v.w;
        }
#pragma unroll
        for (int o = 0; o < D; ++o) {
            float a = acc[o];
#pragma unroll
            for (int i = 0; i < 16; ++i)
                a = fmaf(x[i], Wn[o * D + jc * 16 + i], a);
            acc[o] = a;
        }
    }

    const float c = (float)cnt[node];
#pragma unroll
    for (int j = 0; j < 16; ++j) {
        float4 v;
        v.x = c * acc[4 * j + 0];
        v.y = c * acc[4 * j + 1];
        v.z = c * acc[4 * j + 2];
        v.w = c * acc[4 * j + 3];
        *reinterpret_cast<float4*>(&out[node * D + j * 4]) = v;
    }
}

extern "C" void kernel_launch(void* const* d_in, const int* in_sizes, int n_in,
                              void* d_out, int out_size, void* d_ws, size_t ws_size,
                              hipStream_t stream) {
    const float* nf   = (const float*)d_in[0];  // [100000, 64]
    const void*  eidx = d_in[1];                // [2, 800000] int64 or int32
    const float* Wn   = (const float*)d_in[3];  // [64, 64]
    const float* bn   = (const float*)d_in[4];  // [64]
    float* out = (float*)d_out;                 // [100000, 64] f32

    int* flag = (int*)d_ws;                       // 1 int at offset 0
    int* cnt  = (int*)((char*)d_ws + 256);        // N_NODES ints

    // zero flag + counts
    hipMemsetAsync(d_ws, 0, 256 + (size_t)N_NODES * sizeof(int), stream);

    detect_i64_kernel<<<1, 256, 0, stream>>>((const int*)eidx, flag);

    hist_kernel<<<(N_EDGES + 255) / 256, 256, 0, stream>>>(eidx, flag, cnt);

    proj_kernel<<<(N_NODES + 255) / 256, 256, 0, stream>>>(nf, Wn, bn, cnt, out);
}

// Round 2
// 70.363 us; speedup vs baseline: 1.7308x; 1.7308x over previous
//
#include <hip/hip_runtime.h>
#include <hip/hip_bf16.h>

#define N_NODES 100000
#define N_EDGES 800000
#define D 64

// ---------------------------------------------------------------------------
// softmax(axis=1) over [E,1] == 1.0 identically, so
//   z[n] = count[n] * (node_features[n] @ W_n^T + b_n)
// where count[n] = #edges with node0_idx == n. Attention branch is dead code.
//
// Dispatches: memset(cnt) -> hist -> proj.
// ---------------------------------------------------------------------------

// Histogram of node0_idx with inline int64/int32 detection.
// For an int64 (LE) buffer of values in [0, N_NODES), every odd int32 word
// is 0. Each wave samples 256 odd words; ballot-OR -> wave-uniform verdict.
// False positive requires 256 random indices in [0,1e5) to all be 0: P~0.
__global__ __launch_bounds__(256) void hist_kernel(
        const int* __restrict__ idx32,
        int* __restrict__ cnt) {
    const int lane = threadIdx.x & 63;
    int s = 0;
#pragma unroll
    for (int k = 0; k < 4; ++k) s |= idx32[2 * (lane + 64 * k) + 1];
    const bool is64 = (__ballot(s != 0) == 0ULL);  // wave-uniform

    const int e = blockIdx.x * 256 + threadIdx.x;
    if (e < N_EDGES) {
        const int idx = is64 ? (int)((const long long*)idx32)[e] : idx32[e];
        atomicAdd(&cnt[idx], 1);
    }
}

// Block = 256 threads = 4 waves; block handles 64 nodes.
//   lane  (tid & 63)  -> node within tile
//   wave  (tid >> 6)  -> output chunk oc: outputs [16*oc, 16*oc+16)
// oc is wave-uniform (readfirstlane) so all W_n addresses are uniform ->
// scalar/broadcast loads; inner loop is pure v_fmac_f32.
__global__ __launch_bounds__(256) void proj_kernel(
        const float* __restrict__ nf,   // [N_NODES, 64]
        const float* __restrict__ Wn,   // [64, 64] row-major (W[o][j])
        const float* __restrict__ bn,   // [64]
        const int*   __restrict__ cnt,  // [N_NODES]
        float* __restrict__ out) {      // [N_NODES, 64]
    const int lane = threadIdx.x & 63;
    const int oc = __builtin_amdgcn_readfirstlane(threadIdx.x >> 6);  // 0..3
    const int node = blockIdx.x * 64 + lane;
    if (node >= N_NODES) return;

    const float* __restrict__ Wq = Wn + oc * 16 * D;  // rows [16oc, 16oc+16)
    const float* __restrict__ bq = bn + oc * 16;

    float acc[16];
#pragma unroll
    for (int o = 0; o < 16; ++o) acc[o] = bq[o];  // uniform loads

    const float* __restrict__ xrow = nf + (size_t)node * D;
#pragma unroll
    for (int jc = 0; jc < 4; ++jc) {
        float x[16];
#pragma unroll
        for (int j = 0; j < 4; ++j) {
            const float4 v =
                *reinterpret_cast<const float4*>(xrow + jc * 16 + j * 4);
            x[4 * j + 0] = v.x;
            x[4 * j + 1] = v.y;
            x[4 * j + 2] = v.z;
            x[4 * j + 3] = v.w;
        }
#pragma unroll
        for (int o = 0; o < 16; ++o) {
            float a = acc[o];
#pragma unroll
            for (int i = 0; i < 16; ++i)
                a = fmaf(x[i], Wq[o * D + jc * 16 + i], a);  // sgpr operand
            acc[o] = a;
        }
    }

    const float c = (float)cnt[node];
    float* __restrict__ orow = out + (size_t)node * D + oc * 16;
#pragma unroll
    for (int j = 0; j < 4; ++j) {
        float4 v;
        v.x = c * acc[4 * j + 0];
        v.y = c * acc[4 * j + 1];
        v.z = c * acc[4 * j + 2];
        v.w = c * acc[4 * j + 3];
        *reinterpret_cast<float4*>(orow + j * 4) = v;
    }
}

extern "C" void kernel_launch(void* const* d_in, const int* in_sizes, int n_in,
                              void* d_out, int out_size, void* d_ws, size_t ws_size,
                              hipStream_t stream) {
    const float* nf   = (const float*)d_in[0];  // [100000, 64]
    const int*   eidx = (const int*)d_in[1];    // [2, 800000] int64 or int32
    const float* Wn   = (const float*)d_in[3];  // [64, 64]
    const float* bn   = (const float*)d_in[4];  // [64]
    float* out = (float*)d_out;                 // [100000, 64] f32

    int* cnt = (int*)d_ws;  // N_NODES ints

    hipMemsetAsync(cnt, 0, (size_t)N_NODES * sizeof(int), stream);

    hist_kernel<<<(N_EDGES + 255) / 256, 256, 0, stream>>>(eidx, cnt);

    proj_kernel<<<(N_NODES + 63) / 64, 256, 0, stream>>>(nf, Wn, bn, cnt, out);
}

// Round 3
// 69.991 us; speedup vs baseline: 1.7400x; 1.0053x over previous
//
#include <hip/hip_runtime.h>
#include <hip/hip_bf16.h>

#define N_NODES 100000
#define N_EDGES 800000
#define D 64

// ---------------------------------------------------------------------------
// softmax(axis=1) over [E,1] == 1.0 identically, so
//   z[n] = count[n] * (node_features[n] @ W_n^T + b_n)
// where count[n] = #edges with node0_idx == n. Attention branch is dead code.
//
// Dispatches: zero(cnt) -> hist -> proj.
// (hipMemsetAsync's fillBufferAligned took 39 us for 400 KB -> own kernel.)
// ---------------------------------------------------------------------------

__global__ __launch_bounds__(256) void zero_kernel(int4* __restrict__ cnt4) {
    const int i = blockIdx.x * 256 + threadIdx.x;
    if (i < N_NODES / 4) cnt4[i] = int4{0, 0, 0, 0};
}

// Histogram of node0_idx with inline int64/int32 detection.
// For an int64 (LE) buffer of values in [0, N_NODES), every odd int32 word
// is 0. Each wave samples 256 odd words; ballot-OR -> wave-uniform verdict.
// False positive requires 256 random indices in [0,1e5) to all be 0: P~0.
__global__ __launch_bounds__(256) void hist_kernel(
        const int* __restrict__ idx32,
        int* __restrict__ cnt) {
    const int lane = threadIdx.x & 63;
    int s = 0;
#pragma unroll
    for (int k = 0; k < 4; ++k) s |= idx32[2 * (lane + 64 * k) + 1];
    const bool is64 = (__ballot(s != 0) == 0ULL);  // wave-uniform

    const int e = blockIdx.x * 256 + threadIdx.x;
    if (e < N_EDGES) {
        const int idx = is64 ? (int)((const long long*)idx32)[e] : idx32[e];
        atomicAdd(&cnt[idx], 1);
    }
}

// Block = 256 threads = 4 waves; block handles 64 nodes.
//   lane  (tid & 63)  -> node within tile
//   wave  (tid >> 6)  -> output chunk oc: outputs [16*oc, 16*oc+16)
// oc is wave-uniform (readfirstlane) so all W_n addresses are uniform ->
// scalar/broadcast loads; inner loop is pure v_fmac_f32.
__global__ __launch_bounds__(256) void proj_kernel(
        const float* __restrict__ nf,   // [N_NODES, 64]
        const float* __restrict__ Wn,   // [64, 64] row-major (W[o][j])
        const float* __restrict__ bn,   // [64]
        const int*   __restrict__ cnt,  // [N_NODES]
        float* __restrict__ out) {      // [N_NODES, 64]
    const int lane = threadIdx.x & 63;
    const int oc = __builtin_amdgcn_readfirstlane(threadIdx.x >> 6);  // 0..3
    const int node = blockIdx.x * 64 + lane;
    if (node >= N_NODES) return;

    const float* __restrict__ Wq = Wn + oc * 16 * D;  // rows [16oc, 16oc+16)
    const float* __restrict__ bq = bn + oc * 16;

    float acc[16];
#pragma unroll
    for (int o = 0; o < 16; ++o) acc[o] = bq[o];  // uniform loads

    const float* __restrict__ xrow = nf + (size_t)node * D;
#pragma unroll
    for (int jc = 0; jc < 4; ++jc) {
        float x[16];
#pragma unroll
        for (int j = 0; j < 4; ++j) {
            const float4 v =
                *reinterpret_cast<const float4*>(xrow + jc * 16 + j * 4);
            x[4 * j + 0] = v.x;
            x[4 * j + 1] = v.y;
            x[4 * j + 2] = v.z;
            x[4 * j + 3] = v.w;
        }
#pragma unroll
        for (int o = 0; o < 16; ++o) {
            float a = acc[o];
#pragma unroll
            for (int i = 0; i < 16; ++i)
                a = fmaf(x[i], Wq[o * D + jc * 16 + i], a);  // sgpr operand
            acc[o] = a;
        }
    }

    const float c = (float)cnt[node];
    float* __restrict__ orow = out + (size_t)node * D + oc * 16;
#pragma unroll
    for (int j = 0; j < 4; ++j) {
        float4 v;
        v.x = c * acc[4 * j + 0];
        v.y = c * acc[4 * j + 1];
        v.z = c * acc[4 * j + 2];
        v.w = c * acc[4 * j + 3];
        *reinterpret_cast<float4*>(orow + j * 4) = v;
    }
}

extern "C" void kernel_launch(void* const* d_in, const int* in_sizes, int n_in,
                              void* d_out, int out_size, void* d_ws, size_t ws_size,
                              hipStream_t stream) {
    const float* nf   = (const float*)d_in[0];  // [100000, 64]
    const int*   eidx = (const int*)d_in[1];    // [2, 800000] int64 or int32
    const float* Wn   = (const float*)d_in[3];  // [64, 64]
    const float* bn   = (const float*)d_in[4];  // [64]
    float* out = (float*)d_out;                 // [100000, 64] f32

    int* cnt = (int*)d_ws;  // N_NODES ints (N_NODES % 4 == 0)

    zero_kernel<<<(N_NODES / 4 + 255) / 256, 256, 0, stream>>>((int4*)cnt);

    hist_kernel<<<(N_EDGES + 255) / 256, 256, 0, stream>>>(eidx, cnt);

    proj_kernel<<<(N_NODES + 63) / 64, 256, 0, stream>>>(nf, Wn, bn, cnt, out);
}